// Round 1
// baseline (258.813 us; speedup 1.0000x reference)
//
#include <hip/hip_runtime.h>

// Problem constants (from reference): E = 8*128*128, MLP 16->128->256->128->(32x32)
#define EDGE_FEAT 16
#define H1 128
#define H2 256
#define H3 128
#define OUT_DIM 32
#define ROWS 32   // edges per block

// ---------------------------------------------------------------------------
// Pre-kernel: fold the einsum's inner-sum into W4/b4.
// W4r[k][o] = sum_{i<32} W4[k][o*32+i];  b4r[o] = sum_i b4[o*32+i]
// ---------------------------------------------------------------------------
__global__ void reduce_w4_kernel(const float* __restrict__ W4,
                                 const float* __restrict__ b4,
                                 float* __restrict__ W4r,
                                 float* __restrict__ b4r) {
  int t = blockIdx.x * blockDim.x + threadIdx.x;
  if (t < H3 * OUT_DIM) {
    const float* p = W4 + (size_t)(t >> 5) * 1024 + (size_t)(t & 31) * 32;
    float s = 0.f;
#pragma unroll
    for (int i = 0; i < 32; ++i) s += p[i];
    W4r[t] = s;  // layout W4r[k*32 + o]
  }
  if (t < OUT_DIM) {
    const float* p = b4 + t * 32;
    float s = 0.f;
#pragma unroll
    for (int i = 0; i < 32; ++i) s += p[i];
    b4r[t] = s;
  }
}

// ---------------------------------------------------------------------------
// Fused 4-layer MLP + scale. 256 threads handle ROWS=32 edges.
// Activations live in LDS (ping-pong sA/sB); weights come from L1/L2.
// ---------------------------------------------------------------------------
__global__ __launch_bounds__(256, 3) void mlp_fused_kernel(
    const float* __restrict__ e_vw, const float* __restrict__ h_w,
    const float* __restrict__ W1, const float* __restrict__ b1,
    const float* __restrict__ W2, const float* __restrict__ b2,
    const float* __restrict__ W3, const float* __restrict__ b3,
    const float* __restrict__ W4r, const float* __restrict__ b4r,
    float* __restrict__ out) {
  __shared__ float sIn[ROWS][EDGE_FEAT];   // 2 KB
  __shared__ float sA[ROWS][H1 + 4];       // 16.5 KB (X1, later X3)
  __shared__ float sB[ROWS][H2 + 4];       // 32.5 KB (X2)
  __shared__ float sScale[ROWS];

  const int t = threadIdx.x;
  const size_t row0 = (size_t)blockIdx.x * ROWS;

  // ---- stage inputs ----
  if (t < 128) {
    int r = t >> 2, c = (t & 3) * 4;
    float4 v = *reinterpret_cast<const float4*>(e_vw + (row0 + r) * EDGE_FEAT + c);
    sIn[r][c] = v.x; sIn[r][c + 1] = v.y; sIn[r][c + 2] = v.z; sIn[r][c + 3] = v.w;
  }
  if (t < ROWS) {
    size_t e = row0 + t;
    // h_w_rows[e,:] == h_w[e>>7][(e&127)>>2] (constant across the row)
    sScale[t] = h_w[(e >> 7) * 32 + ((e & 127) >> 2)];
  }
  __syncthreads();

  // ---- Layer 1: 16 -> 128, ReLU.  cg=t&63 -> 2 cols, rg=t>>6 -> 8 rows ----
  {
    const int cg = t & 63, rg = t >> 6;
    const int c0 = cg * 2, r0 = rg * 8;
    float acc[8][2] = {};
#pragma unroll
    for (int k = 0; k < EDGE_FEAT; ++k) {
      float2 w = *reinterpret_cast<const float2*>(W1 + (size_t)k * H1 + c0);
#pragma unroll
      for (int r = 0; r < 8; ++r) {
        float a = sIn[r0 + r][k];
        acc[r][0] += a * w.x; acc[r][1] += a * w.y;
      }
    }
    float2 bb = *reinterpret_cast<const float2*>(b1 + c0);
#pragma unroll
    for (int r = 0; r < 8; ++r) {
      sA[r0 + r][c0]     = fmaxf(acc[r][0] + bb.x, 0.f);
      sA[r0 + r][c0 + 1] = fmaxf(acc[r][1] + bb.y, 0.f);
    }
  }
  __syncthreads();

  // ---- Layer 2: 128 -> 256, ReLU.  cg=t&63 -> 4 cols, rg=t>>6 -> 8 rows ----
  {
    const int cg = t & 63, rg = t >> 6;
    const int c0 = cg * 4, r0 = rg * 8;
    float acc[8][4] = {};
#pragma unroll 4
    for (int k = 0; k < H1; ++k) {
      float4 w = *reinterpret_cast<const float4*>(W2 + (size_t)k * H2 + c0);
#pragma unroll
      for (int r = 0; r < 8; ++r) {
        float a = sA[r0 + r][k];
        acc[r][0] += a * w.x; acc[r][1] += a * w.y;
        acc[r][2] += a * w.z; acc[r][3] += a * w.w;
      }
    }
    float4 bb = *reinterpret_cast<const float4*>(b2 + c0);
#pragma unroll
    for (int r = 0; r < 8; ++r) {
      float4 v;
      v.x = fmaxf(acc[r][0] + bb.x, 0.f);
      v.y = fmaxf(acc[r][1] + bb.y, 0.f);
      v.z = fmaxf(acc[r][2] + bb.z, 0.f);
      v.w = fmaxf(acc[r][3] + bb.w, 0.f);
      *reinterpret_cast<float4*>(&sB[r0 + r][c0]) = v;
    }
  }
  __syncthreads();

  // ---- Layer 3: 256 -> 128, ReLU.  cg=t&31 -> 4 cols, rg=t>>5 -> 4 rows ----
  {
    const int cg = t & 31, rg = t >> 5;
    const int c0 = cg * 4, r0 = rg * 4;
    float acc[4][4] = {};
#pragma unroll 4
    for (int k = 0; k < H2; ++k) {
      float4 w = *reinterpret_cast<const float4*>(W3 + (size_t)k * H3 + c0);
#pragma unroll
      for (int r = 0; r < 4; ++r) {
        float a = sB[r0 + r][k];
        acc[r][0] += a * w.x; acc[r][1] += a * w.y;
        acc[r][2] += a * w.z; acc[r][3] += a * w.w;
      }
    }
    float4 bb = *reinterpret_cast<const float4*>(b3 + c0);
#pragma unroll
    for (int r = 0; r < 4; ++r) {
      float4 v;
      v.x = fmaxf(acc[r][0] + bb.x, 0.f);
      v.y = fmaxf(acc[r][1] + bb.y, 0.f);
      v.z = fmaxf(acc[r][2] + bb.z, 0.f);
      v.w = fmaxf(acc[r][3] + bb.w, 0.f);
      *reinterpret_cast<float4*>(&sA[r0 + r][c0]) = v;
    }
  }
  __syncthreads();

  // ---- Layer 4: 128 -> 32, then scale by s_e.  cg=t&31 -> 1 col, rg -> 4 rows
  {
    const int cg = t & 31, rg = t >> 5;
    const int r0 = rg * 4;
    float acc[4] = {};
#pragma unroll 4
    for (int k = 0; k < H3; ++k) {
      float w = W4r[k * 32 + cg];
#pragma unroll
      for (int r = 0; r < 4; ++r) acc[r] += sA[r0 + r][k] * w;
    }
    float bb = b4r[cg];
#pragma unroll
    for (int r = 0; r < 4; ++r) {
      int row = r0 + r;
      out[(row0 + row) * OUT_DIM + cg] = sScale[row] * (acc[r] + bb);
    }
  }
}

// ---------------------------------------------------------------------------
extern "C" void kernel_launch(void* const* d_in, const int* in_sizes, int n_in,
                              void* d_out, int out_size, void* d_ws, size_t ws_size,
                              hipStream_t stream) {
  // setup_inputs order: h_v, h_w, e_vw, W1, b1, W2, b2, W3, b3, W4, b4
  const float* h_w  = (const float*)d_in[1];
  const float* e_vw = (const float*)d_in[2];
  const float* W1   = (const float*)d_in[3];
  const float* b1   = (const float*)d_in[4];
  const float* W2   = (const float*)d_in[5];
  const float* b2   = (const float*)d_in[6];
  const float* W3   = (const float*)d_in[7];
  const float* b3   = (const float*)d_in[8];
  const float* W4   = (const float*)d_in[9];
  const float* b4   = (const float*)d_in[10];
  float* out = (float*)d_out;

  float* W4r = (float*)d_ws;              // 4096 floats
  float* b4r = W4r + H3 * OUT_DIM;        // 32 floats

  const int E = in_sizes[2] / EDGE_FEAT;  // 131072

  hipLaunchKernelGGL(reduce_w4_kernel, dim3(16), dim3(256), 0, stream, W4, b4, W4r, b4r);
  hipLaunchKernelGGL(mlp_fused_kernel, dim3(E / ROWS), dim3(256), 0, stream,
                     e_vw, h_w, W1, b1, W2, b2, W3, b3, W4r, b4r, out);
}

// Round 3
// 49.532 us; speedup vs baseline: 5.2251x; 5.2251x over previous
//
#include <hip/hip_runtime.h>

// E = 8*128*128 edges; MLP 16->128->256->128->(32x32 folded to 32)
// Strategy: fp16 MFMA (16x16x32) for all 4 layers, weights pre-swizzled into
// fragment order, activations in LDS fp16, one 16-row stripe per wave.

typedef _Float16 f16;
typedef _Float16 f16x8 __attribute__((ext_vector_type(8)));
typedef float f32x4 __attribute__((ext_vector_type(4)));

#define OFF_W1S 0        // [8 ct][64 lane][8]   (K=16 zero-padded to 32)
#define OFF_W2S 4096     // [16 ct][4 kt][64][8]
#define OFF_W3S 36864    // [8 ct][8 kt][64][8]
#define OFF_W4S 69632    // [2 ct][4 kt][64][8]  (W4 folded over inner i)
#define WS_HALFS 73728

union U16x8 { struct { uint2 lo, hi; } p; f16x8 v; };

// ---------------------------------------------------------------------------
// Pre-kernel: fold W4 over i, convert all weights to fp16 in MFMA B-fragment
// order: frag element j of lane l for col-tile ct, k-tile kt is
// W[kt*32 + (l>>4)*8 + j][ct*16 + (l&15)].
// ---------------------------------------------------------------------------
__global__ void prep_kernel(const float* __restrict__ W1, const float* __restrict__ W2,
                            const float* __restrict__ W3, const float* __restrict__ W4,
                            const float* __restrict__ b4, f16* __restrict__ wsh,
                            float* __restrict__ b4r) {
  int t = blockIdx.x * 256 + threadIdx.x;
  if (t < 4096) {                       // W1s (K padded 16->32 with zeros)
    int j = t & 7, l = (t >> 3) & 63, ct = t >> 9;
    int k = ((l >> 4) & 3) * 8 + j, c = ct * 16 + (l & 15);
    wsh[OFF_W1S + t] = (k < 16) ? (f16)W1[k * 128 + c] : (f16)0.f;
  } else if (t < 36864) {               // W2s
    int s = t - 4096;
    int j = s & 7, l = (s >> 3) & 63, kt = (s >> 9) & 3, ct = s >> 11;
    int k = kt * 32 + ((l >> 4) & 3) * 8 + j, c = ct * 16 + (l & 15);
    wsh[t] = (f16)W2[k * 256 + c];
  } else if (t < 69632) {               // W3s
    int s = t - 36864;
    int j = s & 7, l = (s >> 3) & 63, kt = (s >> 9) & 7, ct = s >> 12;
    int k = kt * 32 + ((l >> 4) & 3) * 8 + j, c = ct * 16 + (l & 15);
    wsh[t] = (f16)W3[k * 128 + c];
  } else if (t < 73728) {               // W4rs (folded)
    int s = t - 69632;
    int j = s & 7, l = (s >> 3) & 63, kt = (s >> 9) & 3, ct = s >> 11;
    int k = kt * 32 + ((l >> 4) & 3) * 8 + j, o = ct * 16 + (l & 15);
    float a = 0.f;
#pragma unroll
    for (int i = 0; i < 32; ++i) a += W4[k * 1024 + o * 32 + i];
    wsh[t] = (f16)a;
  }
  if (t < 32) {
    float a = 0.f;
#pragma unroll
    for (int i = 0; i < 32; ++i) a += b4[t * 32 + i];
    b4r[t] = a;
  }
}

// ---------------------------------------------------------------------------
// Fused MLP: 64 rows/block, 4 waves, wave w owns rows [w*16, w*16+16).
// A-frags read from LDS (2x ds_read_b64), B-frags one coalesced 16B global
// load from the pre-swizzled table (L2-resident, shared by all blocks).
// ---------------------------------------------------------------------------
__global__ __launch_bounds__(256, 2) void mlp_mfma_kernel(
    const float* __restrict__ e_vw, const float* __restrict__ h_w,
    const float* __restrict__ b1, const float* __restrict__ b2,
    const float* __restrict__ b3,
    const f16* __restrict__ wsh, const float* __restrict__ b4r,
    float* __restrict__ out) {
  __shared__ f16 sX0[64 * 36];    // input, cols 16..31 zeroed (K-pad)
  __shared__ f16 sX1[64 * 132];
  __shared__ f16 sX2[64 * 260];
  __shared__ f16 sX3[64 * 132];

  const int l  = threadIdx.x & 63;
  const int w  = threadIdx.x >> 6;
  const int e0 = l & 15;          // A-row / C-col within tile
  const int kg = l >> 4;          // k-group (also C row-group)
  const int row0 = blockIdx.x * 64;

  // ---- stage e_vw (fp32 -> fp16), zero the K-pad ----
  {
    int rl = w * 16 + (l >> 2);
    int c4 = (l & 3) * 4;
    float4 v = *reinterpret_cast<const float4*>(e_vw + (size_t)(row0 + rl) * 16 + c4);
    union { f16 h[4]; uint2 u; } pk;
    pk.h[0] = (f16)v.x; pk.h[1] = (f16)v.y; pk.h[2] = (f16)v.z; pk.h[3] = (f16)v.w;
    *reinterpret_cast<uint2*>(sX0 + rl * 36 + c4) = pk.u;
    uint2 z; z.x = 0u; z.y = 0u;
    *reinterpret_cast<uint2*>(sX0 + rl * 36 + 16 + c4) = z;
  }
  __syncthreads();

  // ---- L1: 16 -> 128 ----
  {
    const f16* pa = sX0 + (w * 16 + e0) * 36 + kg * 8;
    U16x8 a; a.p.lo = *(const uint2*)pa; a.p.hi = *(const uint2*)(pa + 4);
    const f16x8* wp = (const f16x8*)(wsh + OFF_W1S);
#pragma unroll
    for (int ct = 0; ct < 8; ++ct) {
      f32x4 acc = {0.f, 0.f, 0.f, 0.f};
      acc = __builtin_amdgcn_mfma_f32_16x16x32_f16(a.v, wp[ct * 64 + l], acc, 0, 0, 0);
      int col = ct * 16 + e0;
      float bias = b1[col];
#pragma unroll
      for (int r = 0; r < 4; ++r)
        sX1[(w * 16 + kg * 4 + r) * 132 + col] = (f16)fmaxf(acc[r] + bias, 0.f);
    }
  }
  __syncthreads();

  // ---- L2: 128 -> 256 ----
  {
    const f16* pa = sX1 + (w * 16 + e0) * 132 + kg * 8;
    U16x8 a[4];
#pragma unroll
    for (int kt = 0; kt < 4; ++kt) {
      a[kt].p.lo = *(const uint2*)(pa + kt * 32);
      a[kt].p.hi = *(const uint2*)(pa + kt * 32 + 4);
    }
    const f16x8* wp = (const f16x8*)(wsh + OFF_W2S);
#pragma unroll
    for (int ct = 0; ct < 16; ++ct) {
      f32x4 acc = {0.f, 0.f, 0.f, 0.f};
#pragma unroll
      for (int kt = 0; kt < 4; ++kt)
        acc = __builtin_amdgcn_mfma_f32_16x16x32_f16(a[kt].v, wp[(ct * 4 + kt) * 64 + l], acc, 0, 0, 0);
      int col = ct * 16 + e0;
      float bias = b2[col];
#pragma unroll
      for (int r = 0; r < 4; ++r)
        sX2[(w * 16 + kg * 4 + r) * 260 + col] = (f16)fmaxf(acc[r] + bias, 0.f);
    }
  }
  __syncthreads();

  // ---- L3: 256 -> 128 ----
  {
    const f16* pa = sX2 + (w * 16 + e0) * 260 + kg * 8;
    U16x8 a[8];
#pragma unroll
    for (int kt = 0; kt < 8; ++kt) {
      a[kt].p.lo = *(const uint2*)(pa + kt * 32);
      a[kt].p.hi = *(const uint2*)(pa + kt * 32 + 4);
    }
    const f16x8* wp = (const f16x8*)(wsh + OFF_W3S);
#pragma unroll
    for (int ct = 0; ct < 8; ++ct) {
      f32x4 acc = {0.f, 0.f, 0.f, 0.f};
#pragma unroll
      for (int kt = 0; kt < 8; ++kt)
        acc = __builtin_amdgcn_mfma_f32_16x16x32_f16(a[kt].v, wp[(ct * 8 + kt) * 64 + l], acc, 0, 0, 0);
      int col = ct * 16 + e0;
      float bias = b3[col];
#pragma unroll
      for (int r = 0; r < 4; ++r)
        sX3[(w * 16 + kg * 4 + r) * 132 + col] = (f16)fmaxf(acc[r] + bias, 0.f);
    }
  }
  __syncthreads();

  // ---- L4: 128 -> 32 (folded), scale by s_e, store f32 ----
  {
    const f16* pa = sX3 + (w * 16 + e0) * 132 + kg * 8;
    U16x8 a[4];
#pragma unroll
    for (int kt = 0; kt < 4; ++kt) {
      a[kt].p.lo = *(const uint2*)(pa + kt * 32);
      a[kt].p.hi = *(const uint2*)(pa + kt * 32 + 4);
    }
    const f16x8* wp = (const f16x8*)(wsh + OFF_W4S);
    float s[4];
#pragma unroll
    for (int r = 0; r < 4; ++r) {
      int e = row0 + w * 16 + kg * 4 + r;
      s[r] = h_w[(e >> 7) * 32 + ((e & 127) >> 2)];
    }
#pragma unroll
    for (int ct = 0; ct < 2; ++ct) {
      f32x4 acc = {0.f, 0.f, 0.f, 0.f};
#pragma unroll
      for (int kt = 0; kt < 4; ++kt)
        acc = __builtin_amdgcn_mfma_f32_16x16x32_f16(a[kt].v, wp[(ct * 4 + kt) * 64 + l], acc, 0, 0, 0);
      int col = ct * 16 + e0;
      float bb = b4r[col];
#pragma unroll
      for (int r = 0; r < 4; ++r)
        out[(size_t)(row0 + w * 16 + kg * 4 + r) * 32 + col] = s[r] * (acc[r] + bb);
    }
  }
}

// ---------------------------------------------------------------------------
extern "C" void kernel_launch(void* const* d_in, const int* in_sizes, int n_in,
                              void* d_out, int out_size, void* d_ws, size_t ws_size,
                              hipStream_t stream) {
  // inputs: h_v, h_w, e_vw, W1, b1, W2, b2, W3, b3, W4, b4
  const float* h_w  = (const float*)d_in[1];
  const float* e_vw = (const float*)d_in[2];
  const float* W1   = (const float*)d_in[3];
  const float* b1   = (const float*)d_in[4];
  const float* W2   = (const float*)d_in[5];
  const float* b2   = (const float*)d_in[6];
  const float* W3   = (const float*)d_in[7];
  const float* b3   = (const float*)d_in[8];
  const float* W4   = (const float*)d_in[9];
  const float* b4   = (const float*)d_in[10];
  float* out = (float*)d_out;

  f16*   wsh = (f16*)d_ws;
  float* b4r = (float*)((char*)d_ws + (size_t)WS_HALFS * 2);

  const int E = in_sizes[2] / 16;  // 131072

  hipLaunchKernelGGL(prep_kernel, dim3(288), dim3(256), 0, stream,
                     W1, W2, W3, W4, b4, wsh, b4r);
  hipLaunchKernelGGL(mlp_mfma_kernel, dim3(E / 64), dim3(256), 0, stream,
                     e_vw, h_w, b1, b2, b3, wsh, b4r, out);
}

// Round 4
// 35.286 us; speedup vs baseline: 7.3348x; 1.4038x over previous
//
#include <hip/hip_runtime.h>

// E = 8*128*128 edges; MLP 16->128->256->128->(32x32 folded to 32)
// fp16 MFMA 16x16x32 everywhere; weights pre-swizzled into B-fragment order.
// Round 4: column-sliced waves (each wave owns a col-slice, holds its
// B-frags in registers, sweeps all 4 edge tiles) -> 3.8x less L2 weight
// traffic; LDS aliased 70KB -> 49KB -> 3 blocks/CU.

typedef _Float16 f16;
typedef _Float16 f16x8 __attribute__((ext_vector_type(8)));
typedef float f32x4 __attribute__((ext_vector_type(4)));

#define OFF_W1S 0        // [8 ct][64 lane][8]   (K=16 zero-padded to 32)
#define OFF_W2S 4096     // [16 ct][4 kt][64][8]
#define OFF_W3S 36864    // [8 ct][8 kt][64][8]
#define OFF_W4S 69632    // [2 ct][4 kt][64][8]  (W4 folded over inner i)
#define WS_HALFS 73728

union U16x8 { struct { uint2 lo, hi; } p; f16x8 v; };

// ---------------------------------------------------------------------------
// Pre-kernel: fold W4 over i, convert all weights to fp16 in MFMA B-fragment
// order: frag element j of lane l for col-tile ct, k-tile kt is
// W[kt*32 + (l>>4)*8 + j][ct*16 + (l&15)].
// ---------------------------------------------------------------------------
__global__ void prep_kernel(const float* __restrict__ W1, const float* __restrict__ W2,
                            const float* __restrict__ W3, const float* __restrict__ W4,
                            const float* __restrict__ b4, f16* __restrict__ wsh,
                            float* __restrict__ b4r) {
  int t = blockIdx.x * 256 + threadIdx.x;
  if (t < 4096) {                       // W1s (K padded 16->32 with zeros)
    int j = t & 7, l = (t >> 3) & 63, ct = t >> 9;
    int k = ((l >> 4) & 3) * 8 + j, c = ct * 16 + (l & 15);
    wsh[OFF_W1S + t] = (k < 16) ? (f16)W1[k * 128 + c] : (f16)0.f;
  } else if (t < 36864) {               // W2s
    int s = t - 4096;
    int j = s & 7, l = (s >> 3) & 63, kt = (s >> 9) & 3, ct = s >> 11;
    int k = kt * 32 + ((l >> 4) & 3) * 8 + j, c = ct * 16 + (l & 15);
    wsh[t] = (f16)W2[k * 256 + c];
  } else if (t < 69632) {               // W3s
    int s = t - 36864;
    int j = s & 7, l = (s >> 3) & 63, kt = (s >> 9) & 7, ct = s >> 12;
    int k = kt * 32 + ((l >> 4) & 3) * 8 + j, c = ct * 16 + (l & 15);
    wsh[t] = (f16)W3[k * 128 + c];
  } else if (t < 73728) {               // W4rs (folded)
    int s = t - 69632;
    int j = s & 7, l = (s >> 3) & 63, kt = (s >> 9) & 3, ct = s >> 11;
    int k = kt * 32 + ((l >> 4) & 3) * 8 + j, o = ct * 16 + (l & 15);
    float a = 0.f;
#pragma unroll
    for (int i = 0; i < 32; ++i) a += W4[k * 1024 + o * 32 + i];
    wsh[t] = (f16)a;
  }
  if (t < 32) {
    float a = 0.f;
#pragma unroll
    for (int i = 0; i < 32; ++i) a += b4[t * 32 + i];
    b4r[t] = a;
  }
}

// ---------------------------------------------------------------------------
// Fused MLP, 64 rows/block, 4 waves, column-sliced.
//   L1: wave owns cols [w*32, w*32+32)    (2 ct)
//   L2: wave owns cols [w*64, w*64+64)    (4 ct)
//   L3: wave owns cols [w*32, w*32+32)    (2 ct)
//   L4: wave (w&1) owns col-tile, (w>>1) owns row half
// LDS aliasing: P = sX1 and sX3 (stride 132); Q = sX2 (stride 260) with the
// staged input sX0 (stride 36) at its base. Inter-layer barriers make this
// safe (all reads of a region complete before the aliased writer starts).
// ---------------------------------------------------------------------------
__global__ __launch_bounds__(256, 3) void mlp_mfma_kernel(
    const float* __restrict__ e_vw, const float* __restrict__ h_w,
    const float* __restrict__ b1, const float* __restrict__ b2,
    const float* __restrict__ b3,
    const f16* __restrict__ wsh, const float* __restrict__ b4r,
    float* __restrict__ out) {
  __shared__ f16 P[64 * 132];   // 16.5 KB: sX1, later sX3
  __shared__ f16 Q[64 * 260];   // 32.5 KB: sX0 (base), later sX2

  const int l  = threadIdx.x & 63;
  const int w  = threadIdx.x >> 6;
  const int e0 = l & 15;          // A-row / C-col within a 16-tile
  const int kg = l >> 4;          // k-group / C row-group
  const size_t row0 = (size_t)blockIdx.x * 64;

  // ---- stage e_vw (fp32 -> fp16) into Q stride 36, zero the K-pad ----
  {
    int rl = threadIdx.x >> 2;          // 0..63
    int c4 = (threadIdx.x & 3) * 4;     // 0,4,8,12
    float4 v = *reinterpret_cast<const float4*>(e_vw + (row0 + rl) * 16 + c4);
    union { f16 h[4]; uint2 u; } pk;
    pk.h[0] = (f16)v.x; pk.h[1] = (f16)v.y; pk.h[2] = (f16)v.z; pk.h[3] = (f16)v.w;
    *reinterpret_cast<uint2*>(Q + rl * 36 + c4) = pk.u;
    uint2 z; z.x = 0u; z.y = 0u;
    *reinterpret_cast<uint2*>(Q + rl * 36 + 16 + c4) = z;
  }
  __syncthreads();

  // ---- L1: 16 -> 128 ----
  {
    const f16x8* wp = (const f16x8*)(wsh + OFF_W1S);
    f16x8 bfr[2];
#pragma unroll
    for (int c = 0; c < 2; ++c) bfr[c] = wp[(2 * w + c) * 64 + l];
#pragma unroll
    for (int t = 0; t < 4; ++t) {
      const f16* pa = Q + (t * 16 + e0) * 36 + kg * 8;
      U16x8 a; a.p.lo = *(const uint2*)pa; a.p.hi = *(const uint2*)(pa + 4);
#pragma unroll
      for (int c = 0; c < 2; ++c) {
        f32x4 acc = {0.f, 0.f, 0.f, 0.f};
        acc = __builtin_amdgcn_mfma_f32_16x16x32_f16(a.v, bfr[c], acc, 0, 0, 0);
        int col = (2 * w + c) * 16 + e0;
        float bias = b1[col];
#pragma unroll
        for (int r = 0; r < 4; ++r)
          P[(t * 16 + kg * 4 + r) * 132 + col] = (f16)fmaxf(acc[r] + bias, 0.f);
      }
    }
  }
  __syncthreads();

  // ---- L2: 128 -> 256 ----
  {
    const f16x8* wp = (const f16x8*)(wsh + OFF_W2S);
    f16x8 bfr[16];
#pragma unroll
    for (int c = 0; c < 4; ++c)
#pragma unroll
      for (int kt = 0; kt < 4; ++kt)
        bfr[c * 4 + kt] = wp[((4 * w + c) * 4 + kt) * 64 + l];
#pragma unroll
    for (int t = 0; t < 4; ++t) {
      const f16* pa = P + (t * 16 + e0) * 132 + kg * 8;
      U16x8 a[4];
#pragma unroll
      for (int kt = 0; kt < 4; ++kt) {
        a[kt].p.lo = *(const uint2*)(pa + kt * 32);
        a[kt].p.hi = *(const uint2*)(pa + kt * 32 + 4);
      }
#pragma unroll
      for (int c = 0; c < 4; ++c) {
        f32x4 acc = {0.f, 0.f, 0.f, 0.f};
#pragma unroll
        for (int kt = 0; kt < 4; ++kt)
          acc = __builtin_amdgcn_mfma_f32_16x16x32_f16(a[kt].v, bfr[c * 4 + kt], acc, 0, 0, 0);
        int col = (4 * w + c) * 16 + e0;
        float bias = b2[col];
#pragma unroll
        for (int r = 0; r < 4; ++r)
          Q[(t * 16 + kg * 4 + r) * 260 + col] = (f16)fmaxf(acc[r] + bias, 0.f);
      }
    }
  }
  __syncthreads();

  // ---- L3: 256 -> 128 ----
  {
    const f16x8* wp = (const f16x8*)(wsh + OFF_W3S);
    f16x8 bfr[16];
#pragma unroll
    for (int c = 0; c < 2; ++c)
#pragma unroll
      for (int kt = 0; kt < 8; ++kt)
        bfr[c * 8 + kt] = wp[((2 * w + c) * 8 + kt) * 64 + l];
#pragma unroll
    for (int t = 0; t < 4; ++t) {
      const f16* pa = Q + (t * 16 + e0) * 260 + kg * 8;
      U16x8 a[8];
#pragma unroll
      for (int kt = 0; kt < 8; ++kt) {
        a[kt].p.lo = *(const uint2*)(pa + kt * 32);
        a[kt].p.hi = *(const uint2*)(pa + kt * 32 + 4);
      }
#pragma unroll
      for (int c = 0; c < 2; ++c) {
        f32x4 acc = {0.f, 0.f, 0.f, 0.f};
#pragma unroll
        for (int kt = 0; kt < 8; ++kt)
          acc = __builtin_amdgcn_mfma_f32_16x16x32_f16(a[kt].v, bfr[c * 8 + kt], acc, 0, 0, 0);
        int col = (2 * w + c) * 16 + e0;
        float bias = b3[col];
#pragma unroll
        for (int r = 0; r < 4; ++r)
          P[(t * 16 + kg * 4 + r) * 132 + col] = (f16)fmaxf(acc[r] + bias, 0.f);
      }
    }
  }
  __syncthreads();

  // ---- L4: 128 -> 32 (folded), scale by s_e, store f32 ----
  {
    const f16x8* wp = (const f16x8*)(wsh + OFF_W4S);
    const int ct = w & 1;
    const int tb = (w >> 1) * 2;
    f16x8 bfr[4];
#pragma unroll
    for (int kt = 0; kt < 4; ++kt) bfr[kt] = wp[(ct * 4 + kt) * 64 + l];
#pragma unroll
    for (int ti = 0; ti < 2; ++ti) {
      int t = tb + ti;
      const f16* pa = P + (t * 16 + e0) * 132 + kg * 8;
      U16x8 a[4];
#pragma unroll
      for (int kt = 0; kt < 4; ++kt) {
        a[kt].p.lo = *(const uint2*)(pa + kt * 32);
        a[kt].p.hi = *(const uint2*)(pa + kt * 32 + 4);
      }
      f32x4 acc = {0.f, 0.f, 0.f, 0.f};
#pragma unroll
      for (int kt = 0; kt < 4; ++kt)
        acc = __builtin_amdgcn_mfma_f32_16x16x32_f16(a[kt].v, bfr[kt], acc, 0, 0, 0);
      int col = ct * 16 + e0;
      float bb = b4r[col];
#pragma unroll
      for (int r = 0; r < 4; ++r) {
        size_t e = row0 + t * 16 + kg * 4 + r;
        float s = h_w[(e >> 7) * 32 + ((e & 127) >> 2)];
        out[e * 32 + col] = s * (acc[r] + bb);
      }
    }
  }
}

// ---------------------------------------------------------------------------
extern "C" void kernel_launch(void* const* d_in, const int* in_sizes, int n_in,
                              void* d_out, int out_size, void* d_ws, size_t ws_size,
                              hipStream_t stream) {
  // inputs: h_v, h_w, e_vw, W1, b1, W2, b2, W3, b3, W4, b4
  const float* h_w  = (const float*)d_in[1];
  const float* e_vw = (const float*)d_in[2];
  const float* W1   = (const float*)d_in[3];
  const float* b1   = (const float*)d_in[4];
  const float* W2   = (const float*)d_in[5];
  const float* b2   = (const float*)d_in[6];
  const float* W3   = (const float*)d_in[7];
  const float* b3   = (const float*)d_in[8];
  const float* W4   = (const float*)d_in[9];
  const float* b4   = (const float*)d_in[10];
  float* out = (float*)d_out;

  f16*   wsh = (f16*)d_ws;
  float* b4r = (float*)((char*)d_ws + (size_t)WS_HALFS * 2);

  const int E = in_sizes[2] / 16;  // 131072

  hipLaunchKernelGGL(prep_kernel, dim3(288), dim3(256), 0, stream,
                     W1, W2, W3, W4, b4, wsh, b4r);
  hipLaunchKernelGGL(mlp_mfma_kernel, dim3(E / 64), dim3(256), 0, stream,
                     e_vw, h_w, b1, b2, b3, wsh, b4r, out);
}

// Round 6
// 32.635 us; speedup vs baseline: 7.9306x; 1.0812x over previous
//
#include <hip/hip_runtime.h>

// E = 8*128*128 edges; MLP 16->128->256->128->(32x32 folded to 32)
// fp16 MFMA 16x16x32; weights pre-swizzled into fragment order.
// Round 6: same as round 5 (swapped-operand MFMA -> lane-local edge rows,
// packed cvt_pkrtz epilogue, ds_write_b64, coalesced float4 L4 stores,
// b1 folded into padded-K slot) with the cvt_pkrtz return type fixed
// (__fp16 ext_vector, not _Float16 ext_vector).

typedef _Float16 f16;
typedef _Float16 f16x8 __attribute__((ext_vector_type(8)));
typedef __fp16 fp16x2 __attribute__((ext_vector_type(2)));   // cvt_pkrtz return type
typedef float f32x4 __attribute__((ext_vector_type(4)));

#define OFF_W1S 0        // [8 ct][64 lane][8]   (K=16 padded: row16 = b1)
#define OFF_W2S 4096     // [16 ct][4 kt][64][8]
#define OFF_W3S 36864    // [8 ct][8 kt][64][8]
#define OFF_W4S 69632    // [2 ct][4 kt][64][8]  (W4 folded over inner i)
#define WS_HALFS 73728

union U16x8 { struct { uint2 lo, hi; } p; f16x8 v; };
union U32x2 { fp16x2 h2[2]; uint2 u; };

// ---------------------------------------------------------------------------
// Pre-kernel: fold W4 over i, convert weights to fp16 in fragment order:
// element j of lane l for col-tile ct, k-tile kt is
// W[kt*32 + (l>>4)*8 + j][ct*16 + (l&15)].  W1 row 16 carries b1.
// ---------------------------------------------------------------------------
__global__ void prep_kernel(const float* __restrict__ W1, const float* __restrict__ b1,
                            const float* __restrict__ W2, const float* __restrict__ W3,
                            const float* __restrict__ W4, const float* __restrict__ b4,
                            f16* __restrict__ wsh, float* __restrict__ b4r) {
  int t = blockIdx.x * 256 + threadIdx.x;
  if (t < 4096) {                       // W1s (K 16 + bias row + zeros)
    int j = t & 7, l = (t >> 3) & 63, ct = t >> 9;
    int k = ((l >> 4) & 3) * 8 + j, c = ct * 16 + (l & 15);
    wsh[OFF_W1S + t] = (k < 16) ? (f16)W1[k * 128 + c]
                                : (k == 16 ? (f16)b1[c] : (f16)0.f);
  } else if (t < 36864) {               // W2s
    int s = t - 4096;
    int j = s & 7, l = (s >> 3) & 63, kt = (s >> 9) & 3, ct = s >> 11;
    int k = kt * 32 + ((l >> 4) & 3) * 8 + j, c = ct * 16 + (l & 15);
    wsh[t] = (f16)W2[k * 256 + c];
  } else if (t < 69632) {               // W3s
    int s = t - 36864;
    int j = s & 7, l = (s >> 3) & 63, kt = (s >> 9) & 7, ct = s >> 12;
    int k = kt * 32 + ((l >> 4) & 3) * 8 + j, c = ct * 16 + (l & 15);
    wsh[t] = (f16)W3[k * 128 + c];
  } else if (t < 73728) {               // W4rs (folded over i)
    int s = t - 69632;
    int j = s & 7, l = (s >> 3) & 63, kt = (s >> 9) & 3, ct = s >> 11;
    int k = kt * 32 + ((l >> 4) & 3) * 8 + j, o = ct * 16 + (l & 15);
    float a = 0.f;
#pragma unroll
    for (int i = 0; i < 32; ++i) a += W4[k * 1024 + o * 32 + i];
    wsh[t] = (f16)a;
  }
  if (t < 32) {
    float a = 0.f;
#pragma unroll
    for (int i = 0; i < 32; ++i) a += b4[t * 32 + i];
    b4r[t] = a;
  }
}

// ---------------------------------------------------------------------------
// Fused MLP, 64 rows/block, 4 waves, column-sliced; swapped-operand MFMA.
// D = mfma(Wfrag, Xfrag): lane owns edge (l&15) of tile t, out-cols
// ct*16 + (l>>4)*4 .. +3 in acc[0..3].
// ---------------------------------------------------------------------------
__global__ __launch_bounds__(256, 3) void mlp_mfma_kernel(
    const float* __restrict__ e_vw, const float* __restrict__ h_w,
    const float* __restrict__ b2, const float* __restrict__ b3,
    const f16* __restrict__ wsh, const float* __restrict__ b4r,
    float* __restrict__ out) {
  __shared__ f16 P[64 * 132];   // 16.5 KB: X1, later X3
  __shared__ f16 Q[64 * 260];   // 32.5 KB: staged input (stride 36), later X2

  const int l  = threadIdx.x & 63;
  const int w  = threadIdx.x >> 6;
  const int e0 = l & 15;          // edge-within-tile (B-frag col / D col)
  const int kg = l >> 4;          // k-group; D rows kg*4..kg*4+3
  const size_t row0 = (size_t)blockIdx.x * 64;

  // ---- stage e_vw (fp32 -> fp16) into Q stride 36; col16 = 1.0 (bias K-slot)
  {
    int rl = threadIdx.x >> 2;          // 0..63
    int c4 = (threadIdx.x & 3) * 4;     // 0,4,8,12
    float4 v = *reinterpret_cast<const float4*>(e_vw + (row0 + rl) * 16 + c4);
    union { f16 h[4]; uint2 u; } pk;
    pk.h[0] = (f16)v.x; pk.h[1] = (f16)v.y; pk.h[2] = (f16)v.z; pk.h[3] = (f16)v.w;
    *reinterpret_cast<uint2*>(Q + rl * 36 + c4) = pk.u;
    union { f16 h[4]; uint2 u; } z;
    z.h[0] = (c4 == 0) ? (f16)1.f : (f16)0.f; z.h[1] = (f16)0.f;
    z.h[2] = (f16)0.f; z.h[3] = (f16)0.f;
    *reinterpret_cast<uint2*>(Q + rl * 36 + 16 + c4) = z.u;
  }

  // L1 B-frags (weights as A-operand)
  const f16x8* wp1 = (const f16x8*)(wsh + OFF_W1S);
  f16x8 bfr1[2];
#pragma unroll
  for (int c = 0; c < 2; ++c) bfr1[c] = wp1[(2 * w + c) * 64 + l];
  __syncthreads();

  // ---- L1: 16 -> 128 (bias folded; wave owns cols [w*32, w*32+32)) ----
  {
#pragma unroll
    for (int t = 0; t < 4; ++t) {
      const f16* pa = Q + (t * 16 + e0) * 36 + kg * 8;
      U16x8 a; a.p.lo = *(const uint2*)pa; a.p.hi = *(const uint2*)(pa + 4);
#pragma unroll
      for (int c = 0; c < 2; ++c) {
        f32x4 acc = {0.f, 0.f, 0.f, 0.f};
        acc = __builtin_amdgcn_mfma_f32_16x16x32_f16(bfr1[c], a.v, acc, 0, 0, 0);
        U32x2 o;
        o.h2[0] = __builtin_amdgcn_cvt_pkrtz(fmaxf(acc[0], 0.f), fmaxf(acc[1], 0.f));
        o.h2[1] = __builtin_amdgcn_cvt_pkrtz(fmaxf(acc[2], 0.f), fmaxf(acc[3], 0.f));
        *reinterpret_cast<uint2*>(P + (t * 16 + e0) * 132 + (2 * w + c) * 16 + kg * 4) = o.u;
      }
    }
  }
  const f16x8* wp2 = (const f16x8*)(wsh + OFF_W2S);
  f16x8 bfr2[16];
#pragma unroll
  for (int c = 0; c < 4; ++c)
#pragma unroll
    for (int kt = 0; kt < 4; ++kt)
      bfr2[c * 4 + kt] = wp2[((4 * w + c) * 4 + kt) * 64 + l];
  __syncthreads();

  // ---- L2: 128 -> 256 (wave owns cols [w*64, w*64+64)) ----
  {
    float4 bb[4];
#pragma unroll
    for (int c = 0; c < 4; ++c)
      bb[c] = *reinterpret_cast<const float4*>(b2 + (4 * w + c) * 16 + kg * 4);
#pragma unroll
    for (int t = 0; t < 4; ++t) {
      const f16* pa = P + (t * 16 + e0) * 132 + kg * 8;
      U16x8 a[4];
#pragma unroll
      for (int kt = 0; kt < 4; ++kt) {
        a[kt].p.lo = *(const uint2*)(pa + kt * 32);
        a[kt].p.hi = *(const uint2*)(pa + kt * 32 + 4);
      }
#pragma unroll
      for (int c = 0; c < 4; ++c) {
        f32x4 acc = {0.f, 0.f, 0.f, 0.f};
#pragma unroll
        for (int kt = 0; kt < 4; ++kt)
          acc = __builtin_amdgcn_mfma_f32_16x16x32_f16(bfr2[c * 4 + kt], a[kt].v, acc, 0, 0, 0);
        U32x2 o;
        o.h2[0] = __builtin_amdgcn_cvt_pkrtz(fmaxf(acc[0] + bb[c].x, 0.f),
                                             fmaxf(acc[1] + bb[c].y, 0.f));
        o.h2[1] = __builtin_amdgcn_cvt_pkrtz(fmaxf(acc[2] + bb[c].z, 0.f),
                                             fmaxf(acc[3] + bb[c].w, 0.f));
        *reinterpret_cast<uint2*>(Q + (t * 16 + e0) * 260 + (4 * w + c) * 16 + kg * 4) = o.u;
      }
    }
  }
  const f16x8* wp3 = (const f16x8*)(wsh + OFF_W3S);
  f16x8 bfr3[16];
#pragma unroll
  for (int c = 0; c < 2; ++c)
#pragma unroll
    for (int kt = 0; kt < 8; ++kt)
      bfr3[c * 8 + kt] = wp3[((2 * w + c) * 8 + kt) * 64 + l];
  __syncthreads();

  // ---- L3: 256 -> 128 (wave owns cols [w*32, w*32+32)) ----
  {
    float4 bb[2];
#pragma unroll
    for (int c = 0; c < 2; ++c)
      bb[c] = *reinterpret_cast<const float4*>(b3 + (2 * w + c) * 16 + kg * 4);
#pragma unroll
    for (int t = 0; t < 4; ++t) {
      const f16* pa = Q + (t * 16 + e0) * 260 + kg * 8;
      U16x8 a[8];
#pragma unroll
      for (int kt = 0; kt < 8; ++kt) {
        a[kt].p.lo = *(const uint2*)(pa + kt * 32);
        a[kt].p.hi = *(const uint2*)(pa + kt * 32 + 4);
      }
#pragma unroll
      for (int c = 0; c < 2; ++c) {
        f32x4 acc = {0.f, 0.f, 0.f, 0.f};
#pragma unroll
        for (int kt = 0; kt < 8; ++kt)
          acc = __builtin_amdgcn_mfma_f32_16x16x32_f16(bfr3[c * 8 + kt], a[kt].v, acc, 0, 0, 0);
        U32x2 o;
        o.h2[0] = __builtin_amdgcn_cvt_pkrtz(fmaxf(acc[0] + bb[c].x, 0.f),
                                             fmaxf(acc[1] + bb[c].y, 0.f));
        o.h2[1] = __builtin_amdgcn_cvt_pkrtz(fmaxf(acc[2] + bb[c].z, 0.f),
                                             fmaxf(acc[3] + bb[c].w, 0.f));
        *reinterpret_cast<uint2*>(P + (t * 16 + e0) * 132 + (2 * w + c) * 16 + kg * 4) = o.u;
      }
    }
  }
  const f16x8* wp4 = (const f16x8*)(wsh + OFF_W4S);
  const int ct = w & 1;
  const int tb = (w >> 1) * 2;
  f16x8 bfr4[4];
#pragma unroll
  for (int kt = 0; kt < 4; ++kt) bfr4[kt] = wp4[(ct * 4 + kt) * 64 + l];
  __syncthreads();

  // ---- L4: 128 -> 32 (folded), scale by s_e, coalesced float4 store ----
  {
    float4 bb = *reinterpret_cast<const float4*>(b4r + ct * 16 + kg * 4);
#pragma unroll
    for (int ti = 0; ti < 2; ++ti) {
      int t = tb + ti;
      const f16* pa = P + (t * 16 + e0) * 132 + kg * 8;
      U16x8 a[4];
#pragma unroll
      for (int kt = 0; kt < 4; ++kt) {
        a[kt].p.lo = *(const uint2*)(pa + kt * 32);
        a[kt].p.hi = *(const uint2*)(pa + kt * 32 + 4);
      }
      f32x4 acc = {0.f, 0.f, 0.f, 0.f};
#pragma unroll
      for (int kt = 0; kt < 4; ++kt)
        acc = __builtin_amdgcn_mfma_f32_16x16x32_f16(bfr4[kt], a[kt].v, acc, 0, 0, 0);
      size_t e = row0 + t * 16 + e0;
      float s = h_w[(e >> 7) * 32 + ((e & 127) >> 2)];
      float4 st;
      st.x = s * (acc[0] + bb.x); st.y = s * (acc[1] + bb.y);
      st.z = s * (acc[2] + bb.z); st.w = s * (acc[3] + bb.w);
      *reinterpret_cast<float4*>(out + e * 32 + ct * 16 + kg * 4) = st;
    }
  }
}

// ---------------------------------------------------------------------------
extern "C" void kernel_launch(void* const* d_in, const int* in_sizes, int n_in,
                              void* d_out, int out_size, void* d_ws, size_t ws_size,
                              hipStream_t stream) {
  // inputs: h_v, h_w, e_vw, W1, b1, W2, b2, W3, b3, W4, b4
  const float* h_w  = (const float*)d_in[1];
  const float* e_vw = (const float*)d_in[2];
  const float* W1   = (const float*)d_in[3];
  const float* b1   = (const float*)d_in[4];
  const float* W2   = (const float*)d_in[5];
  const float* b2   = (const float*)d_in[6];
  const float* W3   = (const float*)d_in[7];
  const float* b3   = (const float*)d_in[8];
  const float* W4   = (const float*)d_in[9];
  const float* b4   = (const float*)d_in[10];
  float* out = (float*)d_out;

  f16*   wsh = (f16*)d_ws;
  float* b4r = (float*)((char*)d_ws + (size_t)WS_HALFS * 2);

  const int E = in_sizes[2] / 16;  // 131072

  hipLaunchKernelGGL(prep_kernel, dim3(288), dim3(256), 0, stream,
                     W1, b1, W2, W3, W4, b4, wsh, b4r);
  hipLaunchKernelGGL(mlp_mfma_kernel, dim3(E / 64), dim3(256), 0, stream,
                     e_vw, h_w, b2, b3, wsh, b4r, out);
}